// Round 6
// baseline (1651.313 us; speedup 1.0000x reference)
//
#include <hip/hip_runtime.h>
#include <cstdint>

#define B_SZ 256
#define T_SZ 256
#define I_SZ 512
#define H_SZ 512
#define HALF 256

typedef __attribute__((ext_vector_type(8))) __bf16 bf16x8;
typedef __attribute__((ext_vector_type(8))) short short8;
typedef __attribute__((ext_vector_type(4))) float f32x4;
typedef __attribute__((ext_vector_type(4))) unsigned int uint4v;

__device__ __forceinline__ unsigned short f2bf(float f) {
  unsigned int u = __float_as_uint(f);
  u = (u + 0x7FFFu + ((u >> 16) & 1u)) >> 16;   // RNE
  return (unsigned short)u;
}

__device__ __forceinline__ float sigm(float x) {
  return __builtin_amdgcn_rcpf(1.f + __expf(-x));
}
__device__ __forceinline__ float tanh_(float x) {
  float ax = fabsf(x);
  float e = __expf(-2.f * ax);
  float r = (1.f - e) * __builtin_amdgcn_rcpf(1.f + e);
  return copysignf(r, x);
}

// ---------------- prepass: fp32 -> bf16 (8 elems/thread) ----------------
__global__ void cvt_f32_bf16(const float* __restrict__ src, unsigned short* __restrict__ dst) {
  long i = ((long)blockIdx.x * 256 + threadIdx.x) * 8;
  float4 a = *(const float4*)(src + i);
  float4 b = *(const float4*)(src + i + 4);
  unsigned int w0 = (unsigned)f2bf(a.x) | ((unsigned)f2bf(a.y) << 16);
  unsigned int w1 = (unsigned)f2bf(a.z) | ((unsigned)f2bf(a.w) << 16);
  unsigned int w2 = (unsigned)f2bf(b.x) | ((unsigned)f2bf(b.y) << 16);
  unsigned int w3 = (unsigned)f2bf(b.z) | ((unsigned)f2bf(b.w) << 16);
  uint4v v = {w0, w1, w2, w3};
  *(uint4v*)(dst + i) = v;
}

// ---------------- prepass: h0 -> tagged buf1 (tag 0) + POISON buf0 ------------
// Poison kills cross-launch ABA: stale buf0 words from a prior run carry final
// tag 255 == the tag expected at t=255.
__global__ void init_hw(const float* __restrict__ h0, unsigned long long* __restrict__ dst) {
  int i = blockIdx.x * 256 + threadIdx.x;          // 0..65535 words
  unsigned int pw = (unsigned)f2bf(h0[2 * i]) | ((unsigned)f2bf(h0[2 * i + 1]) << 16);
  dst[65536 + i] = (unsigned long long)pw;         // buffer 1: tag 0 | h0 data
  dst[i] = 0xFFFFFFFF00000000ull;                  // buffer 0: poison tag
}

// ---------------- prepass: pack W_ih / W_hh into per-lane MFMA-B fragment order ----
__global__ void pack_w(const float* __restrict__ Wih, const float* __restrict__ Whh,
                       unsigned short* __restrict__ wp, unsigned short* __restrict__ hp) {
  int id = blockIdx.x * 256 + threadIdx.x;        // 0 .. 262143
  int cid = id & 131071;
  const float* W = (id < 131072) ? Wih : Whh;
  unsigned short* D = (id < 131072) ? wp : hp;
  int l  = cid & 63;
  int ks = (cid >> 6) & 15;
  int nt = (cid >> 10) & 1;
  int w  = (cid >> 11) & 3;
  int hg = (cid >> 13) & 15;
  int row = w * 512 + hg * 32 + nt * 16 + (l & 15);
  int k0  = ks * 32 + (l >> 4) * 8;
  const float* src = W + (long)row * 512 + k0;
  unsigned int wd[4];
#pragma unroll
  for (int j = 0; j < 4; ++j) {
    unsigned int lo = f2bf(src[2 * j]);
    unsigned int hi = f2bf(src[2 * j + 1]);
    wd[j] = lo | (hi << 16);
  }
  uint4v v = {wd[0], wd[1], wd[2], wd[3]};
  *(uint4v*)(D + (long)cid * 8) = v;
}

// ---- issue-early poll loads (invisible to compiler waitcnt accounting) ----
#define LDPA(dst, base, OFFSTR) \
  asm volatile("global_load_dwordx2 %0, %1, off offset:" OFFSTR " sc0" : "=v"(dst) : "v"(base))
#define LDPS(dst, base, OFFSTR) \
  asm volatile("global_load_dwordx2 %0, %1, off offset:" OFFSTR " sc0 sc1" : "=v"(dst) : "v"(base))
// x-prefetch loads (normal caching), also invisible
#define LDX16(dst, base, OFFSTR) \
  asm volatile("global_load_dwordx4 %0, %1, off offset:" OFFSTR : "=v"(dst) : "v"(base))

// slow re-poll path (rare in steady state; compiler-managed waits)
template <int SCOPE>
__device__ __forceinline__ void poll_slow(unsigned long long* pv,
                                          const unsigned long long* srcb,
                                          int wv, unsigned tag) {
  bool redo = true;
  while (redo) {
    redo = false;
#pragma unroll
    for (int i = 0; i < 16; ++i) {
      if ((unsigned)(pv[i] >> 32) != tag) {
        const int row = 2 * wv + ((i >> 2) & 1) + (i >> 3) * 8;
        pv[i] = __hip_atomic_load(srcb + row * 256 + (i & 3), __ATOMIC_RELAXED, SCOPE);
        redo = true;
      }
    }
  }
}

template <int SCOPE>
__device__ __forceinline__ void st64(unsigned long long* p, unsigned long long v) {
  __hip_atomic_store(p, v, __ATOMIC_RELAXED, SCOPE);
}

// ---------------- main persistent LSTM kernel ----------------
// grid 256 = 16 batch-groups (bg) x 16 hidden-groups (hg). Block owns batches
// [bg*16,bg*16+16) x hidden [hg*32,hg*32+32). Wave w = gate type. Weights
// resident in registers. h exchanged as TAGGED u64 words ((t+1)<<32 | bf16x2),
// double-buffered by t&1, fire-and-forget publish.
// Recurrence per step: E(t-1) -> detect(t) -> C(t) -> D -> E(t).
// Schedule (all in-loop vmem the compiler must not mis-count is inline asm):
//   loop top : s_waitcnt vmcnt(3) -- EXACT for every thread: each thread issues
//              exactly 1 pub store + 2 out stores after its 16 x loads (uniform
//              publish: even jj stores word0, odd jj stores word1 of the pair).
//              Drains all 16 x loads, never waits on store-acks. t=0 primed by
//              a pre-loop vmcnt(0).
//   polls    : 16 asm dwordx2 sc0 issued BEFORE phase A; 32 MFMAs hide the RT.
//   mid      : vmcnt(0) + sched_barrier(0) (rule-18 fence), single-branch tag
//              check, slow re-poll only if stale.
//   barriers : raw s_barrier with explicit lgkmcnt(0) (LDS-only) -- never
//              drains the in-flight x prefetch (unlike __syncthreads' vmcnt(0)).
//   hpad     : LINEAR layout. For 16-B-aligned ds_read_b128, 64 lanes x 16 B
//              over 8 aligned 4-bank windows makes 8 lanes/window the geometric
//              floor; round-4's XOR "fix" concentrated 16 lanes/window
//              (conflicts 2.1e7 -> 7.1e7). Reverted.
//   MFMA     : 4 independent accumulator chains (even/odd ks) across phases
//              A and C; dependent-chain depth 16 -> 8. Summed before phase D.
// Deadlock-free by round-0 induction: a producer overwrites buffer t&1 only
// after its own poll succeeded, which requires every peer to have consumed
// that buffer's previous generation.
// Scope: one-time handshake counts blocks per XCD (HW_REG_XCC_ID); a group
// whose 16 blocks share one XCD uses AGENT scope (L2), else SYSTEM.
__global__ __launch_bounds__(256, 1) void lstm_main(
    const unsigned short* __restrict__ xb,   // [B][T][I] bf16
    const float* __restrict__ c0,
    const float* __restrict__ b_ih, const float* __restrict__ b_hh,
    const unsigned short* __restrict__ wihp, const unsigned short* __restrict__ whhp,
    unsigned long long* __restrict__ hw64,   // 2 x [16 bg][16 b][256 w] tagged words
    unsigned long long* __restrict__ cnt64,  // [16 groups][8] per-XCD counters
    float* __restrict__ out)
{
  const int tid  = threadIdx.x;
  const int lane = tid & 63;
  const int w    = tid >> 6;           // wave id == gate type (i,f,g,o)
  const int bg   = blockIdx.x & 15;
  const int hg   = blockIdx.x >> 4;
  const int s0   = hg * 32;
  const int q    = lane >> 4;
  const int c16  = lane & 15;

  __shared__ float glds[4 * 528];                       // gates [gate][b*33 + jj]
  __shared__ __align__(16) unsigned int hpad[16 * 260]; // h_{t-1} [b][260 w] linear
  __shared__ int s_path;

  // ---- one-time scope handshake: are all 16 blocks of this group on one XCD?
  int xcd;
  asm volatile("s_getreg_b32 %0, hwreg(20, 0, 32)" : "=s"(xcd));
  xcd &= 15;
  if (tid == 0) {
    unsigned long long inc = 1ull << (8 * xcd);
    __hip_atomic_fetch_add(&cnt64[bg * 8], inc, __ATOMIC_RELAXED, __HIP_MEMORY_SCOPE_SYSTEM);
    unsigned long long m;
    do {
      __builtin_amdgcn_s_sleep(2);
      m = __hip_atomic_load(&cnt64[bg * 8], __ATOMIC_RELAXED, __HIP_MEMORY_SCOPE_SYSTEM);
    } while ((unsigned)((m * 0x0101010101010101ull) >> 56) < 16);
    s_path = (m == (16ull << (8 * xcd))) ? 1 : 0;
  }
  __syncthreads();
  const bool agent_path = (s_path != 0);

  // ---- resident weight fragments
  bf16x8 wih[2][16], whh[2][16];
#pragma unroll
  for (int nt = 0; nt < 2; ++nt) {
#pragma unroll
    for (int ks = 0; ks < 16; ++ks) {
      int idc = ((hg * 4 + w) * 2 + nt) * 16 + ks;
      long off = ((long)(idc * 64 + lane)) * 8;
      wih[nt][ks] = __builtin_bit_cast(bf16x8, *(const short8*)(wihp + off));
      whh[nt][ks] = __builtin_bit_cast(bf16x8, *(const short8*)(whhp + off));
    }
  }

  // ---- per-thread recurrent state: 2 items (b = tid>>5 and +8, jj = tid&31)
  const int jj  = tid & 31;
  const int bl0 = tid >> 5;            // 0..7
  const int bglob0 = bg * 16 + bl0;
  const int bglob1 = bglob0 + 8;
  float bias_v[4];
#pragma unroll
  for (int g = 0; g < 4; ++g)
    bias_v[g] = b_ih[g * 512 + s0 + jj] + b_hh[g * 512 + s0 + jj];
  float cst0 = c0[(long)bglob0 * H_SZ + s0 + jj];
  float cst1 = c0[(long)bglob1 * H_SZ + s0 + jj];
  float m0 = -INFINITY, m1 = -INFINITY;

  const unsigned short* xbase = xb + (long)(bg * 16 + c16) * T_SZ * I_SZ + q * 8;

  // consumer-side exchange geometry: thread <-> one producer WAVE
  const int p   = tid >> 4;            // producer block (hg')
  const int wv  = (tid >> 2) & 3;      // producer wave within that block
  const int cq  = tid & 3;             // 16-B quad within the 16-word slice
  const int colbase = p * 16 + cq * 4; // hpad col base (linear)

  // ---- x prefetch for t = 0 (asm, invisible)
  bf16x8 xr[16];
  {
    const unsigned short* xn = xbase;
    LDX16(xr[0],  xn, "0");   LDX16(xr[1],  xn, "64");
    LDX16(xr[2],  xn, "128"); LDX16(xr[3],  xn, "192");
    LDX16(xr[4],  xn, "256"); LDX16(xr[5],  xn, "320");
    LDX16(xr[6],  xn, "384"); LDX16(xr[7],  xn, "448");
    LDX16(xr[8],  xn, "512"); LDX16(xr[9],  xn, "576");
    LDX16(xr[10], xn, "640"); LDX16(xr[11], xn, "704");
    LDX16(xr[12], xn, "768"); LDX16(xr[13], xn, "832");
    LDX16(xr[14], xn, "896"); LDX16(xr[15], xn, "960");
  }
  // prime t=0: drain the initial prefetch so the in-loop vmcnt(3) is exact
  asm volatile("s_waitcnt vmcnt(0)" ::: "memory");
  __builtin_amdgcn_sched_barrier(0);

#pragma unroll 1
  for (int t = 0; t < T_SZ; ++t) {
    // ---- loop top: drain the 16 x loads; skip the 3 store-acks (1 pub + 2 out)
    asm volatile("s_waitcnt vmcnt(3)" ::: "memory");
    __builtin_amdgcn_sched_barrier(0);

    // ---- issue early polls for h_{t-1} (tag t, buffer (t+1)&1)
    const unsigned long long* srcb = hw64 + ((t + 1) & 1) * 65536 + bg * 4096 + colbase;
    const unsigned long long* blo = srcb + 2 * wv * 256;   // rows 2wv, 2wv+1
    const unsigned long long* bhi = blo + 8 * 256;         // rows 2wv+8, 2wv+9
    unsigned long long pv[16];
    if (agent_path) {
      LDPA(pv[0],  blo, "0");    LDPA(pv[1],  blo, "8");
      LDPA(pv[2],  blo, "16");   LDPA(pv[3],  blo, "24");
      LDPA(pv[4],  blo, "2048"); LDPA(pv[5],  blo, "2056");
      LDPA(pv[6],  blo, "2064"); LDPA(pv[7],  blo, "2072");
      LDPA(pv[8],  bhi, "0");    LDPA(pv[9],  bhi, "8");
      LDPA(pv[10], bhi, "16");   LDPA(pv[11], bhi, "24");
      LDPA(pv[12], bhi, "2048"); LDPA(pv[13], bhi, "2056");
      LDPA(pv[14], bhi, "2064"); LDPA(pv[15], bhi, "2072");
    } else {
      LDPS(pv[0],  blo, "0");    LDPS(pv[1],  blo, "8");
      LDPS(pv[2],  blo, "16");   LDPS(pv[3],  blo, "24");
      LDPS(pv[4],  blo, "2048"); LDPS(pv[5],  blo, "2056");
      LDPS(pv[6],  blo, "2064"); LDPS(pv[7],  blo, "2072");
      LDPS(pv[8],  bhi, "0");    LDPS(pv[9],  bhi, "8");
      LDPS(pv[10], bhi, "16");   LDPS(pv[11], bhi, "24");
      LDPS(pv[12], bhi, "2048"); LDPS(pv[13], bhi, "2056");
      LDPS(pv[14], bhi, "2064"); LDPS(pv[15], bhi, "2072");
    }

    // ---- phase A: x projection, 4 independent accumulator chains
    f32x4 a0a = {0.f, 0.f, 0.f, 0.f};
    f32x4 a0b = {0.f, 0.f, 0.f, 0.f};
    f32x4 a1a = {0.f, 0.f, 0.f, 0.f};
    f32x4 a1b = {0.f, 0.f, 0.f, 0.f};
#pragma unroll
    for (int ks = 0; ks < 16; ks += 2) {
      a0a = __builtin_amdgcn_mfma_f32_16x16x32_bf16(xr[ks],     wih[0][ks],     a0a, 0, 0, 0);
      a1a = __builtin_amdgcn_mfma_f32_16x16x32_bf16(xr[ks],     wih[1][ks],     a1a, 0, 0, 0);
      a0b = __builtin_amdgcn_mfma_f32_16x16x32_bf16(xr[ks + 1], wih[0][ks + 1], a0b, 0, 0, 0);
      a1b = __builtin_amdgcn_mfma_f32_16x16x32_bf16(xr[ks + 1], wih[1][ks + 1], a1b, 0, 0, 0);
    }

    // ---- polls complete; fence against VALU hoisting (rule 18)
    asm volatile("s_waitcnt vmcnt(0)" ::: "memory");
    __builtin_amdgcn_sched_barrier(0);

    // ---- tag check: single branch on AND of 16 compares (steady state: fresh)
    {
      unsigned ok = 1u;
#pragma unroll
      for (int i = 0; i < 16; ++i) ok &= ((unsigned)(pv[i] >> 32) == (unsigned)t) ? 1u : 0u;
      if (__builtin_expect(ok == 0u, 0)) {
        if (agent_path) poll_slow<__HIP_MEMORY_SCOPE_AGENT>(pv, srcb, wv, (unsigned)t);
        else            poll_slow<__HIP_MEMORY_SCOPE_SYSTEM>(pv, srcb, wv, (unsigned)t);
      }
    }

    // ---- stage to LDS (linear layout)
#pragma unroll
    for (int g = 0; g < 4; ++g) {
      const int row = 2 * wv + (g & 1) + (g >> 1) * 8;
      uint4v d = {(unsigned int)pv[g * 4 + 0], (unsigned int)pv[g * 4 + 1],
                  (unsigned int)pv[g * 4 + 2], (unsigned int)pv[g * 4 + 3]};
      *(uint4v*)(hpad + row * 260 + colbase) = d;
    }
    // raw barrier: LDS-only wait, x prefetch stays untouched
    asm volatile("s_waitcnt lgkmcnt(0)" ::: "memory");
    __builtin_amdgcn_s_barrier();
    asm volatile("" ::: "memory");
    __builtin_amdgcn_sched_barrier(0);

    // ---- x_{t+1} prefetch (asm, invisible; retired by next loop-top vmcnt(3))
    {
      const unsigned short* xn = xbase + (long)(t + 1 < T_SZ ? t + 1 : t) * I_SZ;
      LDX16(xr[0],  xn, "0");   LDX16(xr[1],  xn, "64");
      LDX16(xr[2],  xn, "128"); LDX16(xr[3],  xn, "192");
      LDX16(xr[4],  xn, "256"); LDX16(xr[5],  xn, "320");
      LDX16(xr[6],  xn, "384"); LDX16(xr[7],  xn, "448");
      LDX16(xr[8],  xn, "512"); LDX16(xr[9],  xn, "576");
      LDX16(xr[10], xn, "640"); LDX16(xr[11], xn, "704");
      LDX16(xr[12], xn, "768"); LDX16(xr[13], xn, "832");
      LDX16(xr[14], xn, "896"); LDX16(xr[15], xn, "960");
    }

    // ---- phase C: recurrent projection from LDS, same 4 chains
    const unsigned int* hrow = hpad + c16 * 260;
#pragma unroll
    for (int ks = 0; ks < 16; ks += 2) {
      bf16x8 aa = __builtin_bit_cast(bf16x8, *(const short8*)(hrow + ks * 16 + q * 4));
      bf16x8 ab = __builtin_bit_cast(bf16x8, *(const short8*)(hrow + (ks + 1) * 16 + q * 4));
      a0a = __builtin_amdgcn_mfma_f32_16x16x32_bf16(aa, whh[0][ks],     a0a, 0, 0, 0);
      a1a = __builtin_amdgcn_mfma_f32_16x16x32_bf16(aa, whh[1][ks],     a1a, 0, 0, 0);
      a0b = __builtin_amdgcn_mfma_f32_16x16x32_bf16(ab, whh[0][ks + 1], a0b, 0, 0, 0);
      a1b = __builtin_amdgcn_mfma_f32_16x16x32_bf16(ab, whh[1][ks + 1], a1b, 0, 0, 0);
    }
    f32x4 acc0 = a0a + a0b;
    f32x4 acc1 = a1a + a1b;

    // ---- phase D: gates -> LDS (D layout: row=q*4+r (batch), col=lane&15)
#pragma unroll
    for (int r = 0; r < 4; ++r) {
      glds[w * 528 + (q * 4 + r) * 33 + c16]      = acc0[r];
      glds[w * 528 + (q * 4 + r) * 33 + 16 + c16] = acc1[r];
    }
    asm volatile("s_waitcnt lgkmcnt(0)" ::: "memory");
    __builtin_amdgcn_s_barrier();
    asm volatile("" ::: "memory");
    __builtin_amdgcn_sched_barrier(0);

    // ---- phase E: cell math, then IMMEDIATELY publish h (fire-and-forget).
    //      UNIFORM publish: every thread stores exactly ONE tagged word.
    //      Even jj -> word0 (batch bl0) at d0; odd jj -> word1 (batch bl0+8)
    //      at d0+2048B. Word low half = even column, high half = odd column.
    float hv0, hv1;
#pragma unroll
    for (int it = 0; it < 2; ++it) {
      int b = bl0 + it * 8;
      float gi = glds[0 * 528 + b * 33 + jj] + bias_v[0];
      float gf = glds[1 * 528 + b * 33 + jj] + bias_v[1];
      float gg = glds[2 * 528 + b * 33 + jj] + bias_v[2];
      float go = glds[3 * 528 + b * 33 + jj] + bias_v[3];
      float& cs = it ? cst1 : cst0;
      cs = sigm(gf) * cs + sigm(gi) * tanh_(gg);
      float h = sigm(go) * tanh_(cs);
      if (it) hv1 = h; else hv0 = h;
    }
    {
      float po0 = __shfl_xor(hv0, 1);
      float po1 = __shfl_xor(hv1, 1);
      unsigned long long tagw = (unsigned long long)(t + 1) << 32;
      unsigned long long* d0 = hw64 + (t & 1) * 65536 + bg * 4096
                             + bl0 * 256 + (s0 >> 1) + (jj >> 1);
      unsigned long long wrd;
      unsigned long long* dst;
      if (!(jj & 1)) {   // even lane of the pair: word0 (it=0), low = own value
        wrd = tagw | ((unsigned)f2bf(hv0) | ((unsigned)f2bf(po0) << 16));
        dst = d0;
      } else {           // odd lane: word1 (it=1), low = partner's value
        wrd = tagw | ((unsigned)f2bf(po1) | ((unsigned)f2bf(hv1) << 16));
        dst = d0 + 8 * 256;
      }
      if (agent_path) st64<__HIP_MEMORY_SCOPE_AGENT>(dst, wrd);
      else            st64<__HIP_MEMORY_SCOPE_SYSTEM>(dst, wrd);
    }

    // ---- phase F: outputs (off the critical path, after h is in flight)
#pragma unroll
    for (int it = 0; it < 2; ++it) {
      int b   = bl0 + it * 8;
      int bgl = bg * 16 + b;
      float h = it ? hv1 : hv0;
      float& mm = it ? m1 : m0;
      if (hg < 8) {
        mm = fmaxf(mm, h);
        out[(long)bgl * (T_SZ * HALF) + t * HALF + s0 + jj] = mm;
      } else {
        out[(long)(256 + bgl) * (T_SZ * HALF) + t * HALF + (s0 - 256) + jj] = h;
      }
      if (t == T_SZ - 1) {
        float cs = it ? cst1 : cst0;
        out[33554432L + (long)bgl * H_SZ + s0 + jj] = h;
        out[33554432L + 131072L + (long)bgl * H_SZ + s0 + jj] = cs;
      }
    }
  }
}

extern "C" void kernel_launch(void* const* d_in, const int* in_sizes, int n_in,
                              void* d_out, int out_size, void* d_ws, size_t ws_size,
                              hipStream_t stream) {
  const float* x   = (const float*)d_in[0];
  const float* h0  = (const float*)d_in[1];
  const float* c0  = (const float*)d_in[2];
  const float* Wih = (const float*)d_in[3];
  const float* Whh = (const float*)d_in[4];
  const float* bih = (const float*)d_in[5];
  const float* bhh = (const float*)d_in[6];
  float* out = (float*)d_out;

  char* ws = (char*)d_ws;
  unsigned short* xb     = (unsigned short*)(ws);              // 67,108,864 B
  unsigned short* wihp   = (unsigned short*)(ws + 67108864);   //  2,097,152 B
  unsigned short* whhp   = (unsigned short*)(ws + 69206016);   //  2,097,152 B
  unsigned long long* hw = (unsigned long long*)(ws + 71303168); // 1,048,576 B
  unsigned long long* cn = (unsigned long long*)(ws + 72351744); //     4,096 B

  hipMemsetAsync(cn, 0, 4096, stream);
  cvt_f32_bf16<<<16384, 256, 0, stream>>>(x, xb);              // x -> bf16
  init_hw<<<256, 256, 0, stream>>>(h0, hw);                    // buf1 tag0 + buf0 poison
  pack_w<<<1024, 256, 0, stream>>>(Wih, Whh, wihp, whhp);
  lstm_main<<<256, 256, 0, stream>>>(xb, c0, bih, bhh, wihp, whhp, hw, cn, out);
}

// Round 7
// 1399.191 us; speedup vs baseline: 1.1802x; 1.1802x over previous
//
#include <hip/hip_runtime.h>
#include <cstdint>

#define B_SZ 256
#define T_SZ 256
#define I_SZ 512
#define H_SZ 512
#define HALF 256

typedef __attribute__((ext_vector_type(8))) __bf16 bf16x8;
typedef __attribute__((ext_vector_type(8))) short short8;
typedef __attribute__((ext_vector_type(4))) float f32x4;
typedef __attribute__((ext_vector_type(4))) unsigned int uint4v;

__device__ __forceinline__ unsigned short f2bf(float f) {
  unsigned int u = __float_as_uint(f);
  u = (u + 0x7FFFu + ((u >> 16) & 1u)) >> 16;   // RNE
  return (unsigned short)u;
}

__device__ __forceinline__ float sigm(float x) {
  return __builtin_amdgcn_rcpf(1.f + __expf(-x));
}
__device__ __forceinline__ float tanh_(float x) {
  float ax = fabsf(x);
  float e = __expf(-2.f * ax);
  float r = (1.f - e) * __builtin_amdgcn_rcpf(1.f + e);
  return copysignf(r, x);
}

// ---------------- prepass: fp32 -> bf16 (8 elems/thread) ----------------
__global__ void cvt_f32_bf16(const float* __restrict__ src, unsigned short* __restrict__ dst) {
  long i = ((long)blockIdx.x * 256 + threadIdx.x) * 8;
  float4 a = *(const float4*)(src + i);
  float4 b = *(const float4*)(src + i + 4);
  unsigned int w0 = (unsigned)f2bf(a.x) | ((unsigned)f2bf(a.y) << 16);
  unsigned int w1 = (unsigned)f2bf(a.z) | ((unsigned)f2bf(a.w) << 16);
  unsigned int w2 = (unsigned)f2bf(b.x) | ((unsigned)f2bf(b.y) << 16);
  unsigned int w3 = (unsigned)f2bf(b.z) | ((unsigned)f2bf(b.w) << 16);
  uint4v v = {w0, w1, w2, w3};
  *(uint4v*)(dst + i) = v;
}

// ---------------- prepass: h0 -> tagged buf1 (tag 0) + POISON buf0 ------------
// Poison kills cross-launch ABA: stale buf0 words from a prior run carry final
// tag 255 == the tag expected at t=255.
__global__ void init_hw(const float* __restrict__ h0, unsigned long long* __restrict__ dst) {
  int i = blockIdx.x * 256 + threadIdx.x;          // 0..65535 words
  unsigned int pw = (unsigned)f2bf(h0[2 * i]) | ((unsigned)f2bf(h0[2 * i + 1]) << 16);
  dst[65536 + i] = (unsigned long long)pw;         // buffer 1: tag 0 | h0 data
  dst[i] = 0xFFFFFFFF00000000ull;                  // buffer 0: poison tag
}

// ---------------- prepass: pack W_ih / W_hh into per-lane MFMA-B fragment order ----
__global__ void pack_w(const float* __restrict__ Wih, const float* __restrict__ Whh,
                       unsigned short* __restrict__ wp, unsigned short* __restrict__ hp) {
  int id = blockIdx.x * 256 + threadIdx.x;        // 0 .. 262143
  int cid = id & 131071;
  const float* W = (id < 131072) ? Wih : Whh;
  unsigned short* D = (id < 131072) ? wp : hp;
  int l  = cid & 63;
  int ks = (cid >> 6) & 15;
  int nt = (cid >> 10) & 1;
  int w  = (cid >> 11) & 3;
  int hg = (cid >> 13) & 15;
  int row = w * 512 + hg * 32 + nt * 16 + (l & 15);
  int k0  = ks * 32 + (l >> 4) * 8;
  const float* src = W + (long)row * 512 + k0;
  unsigned int wd[4];
#pragma unroll
  for (int j = 0; j < 4; ++j) {
    unsigned int lo = f2bf(src[2 * j]);
    unsigned int hi = f2bf(src[2 * j + 1]);
    wd[j] = lo | (hi << 16);
  }
  uint4v v = {wd[0], wd[1], wd[2], wd[3]};
  *(uint4v*)(D + (long)cid * 8) = v;
}

// ---- issue-early poll loads (invisible to compiler waitcnt accounting) ----
#define LDPA(dst, base, OFFSTR) \
  asm volatile("global_load_dwordx2 %0, %1, off offset:" OFFSTR " sc0" : "=v"(dst) : "v"(base))
#define LDPS(dst, base, OFFSTR) \
  asm volatile("global_load_dwordx2 %0, %1, off offset:" OFFSTR " sc0 sc1" : "=v"(dst) : "v"(base))
// x-prefetch loads (normal caching), also invisible
#define LDX16(dst, base, OFFSTR) \
  asm volatile("global_load_dwordx4 %0, %1, off offset:" OFFSTR : "=v"(dst) : "v"(base))

// re-poll path for stale words (rare in steady state; compiler-managed waits)
template <int SCOPE>
__device__ __forceinline__ void poll_check(unsigned long long* pv,
                                           const unsigned long long* srcb,
                                           int wv, unsigned tag) {
  bool redo = true;
  while (redo) {
    redo = false;
#pragma unroll
    for (int i = 0; i < 16; ++i) {
      if ((unsigned)(pv[i] >> 32) != tag) {
        const int row = 2 * wv + ((i >> 2) & 1) + (i >> 3) * 8;
        pv[i] = __hip_atomic_load(srcb + row * 256 + (i & 3), __ATOMIC_RELAXED, SCOPE);
        redo = true;
      }
    }
  }
}

template <int SCOPE>
__device__ __forceinline__ void st64(unsigned long long* p, unsigned long long v) {
  __hip_atomic_store(p, v, __ATOMIC_RELAXED, SCOPE);
}

// ---------------- main persistent LSTM kernel ----------------
// 256 persistent blocks; the (bg,hg) role of each block is assigned AT RUNTIME
// from the measured XCD (HW_REG_XCC_ID):
//   1. each block takes a local rank on its XCD (byte-packed atomic counter),
//   2. all 256 blocks rendezvous on a global total counter (release/acquire),
//   3. slot = (sum of counts of lower XCDs) + rank;  bg = slot>>4, hg = slot&15.
// With even dispatch (32 blocks/XCD) every 16-block bg-group lands on ONE XCD
// -> all h-exchange polls/publishes are XCD-L2-local (agent scope), and the
// "slowest straddling group sets kernel time" tail is eliminated. Uneven
// dispatch stays correct: slots are bijective and each group checks whether
// its slot range fits inside one XCD's run (else system scope).
// Exchange protocol (round-0/4 proven): h as TAGGED u64 words ((t+1)<<32 |
// bf16x2), double-buffered by t&1, fire-and-forget publish, consumers poll the
// data words for tag equality (1 L2 hop). Deadlock/ABA-free by induction;
// buf0 poisoned at launch (cross-launch ABA).
// Schedule per step: issue-early polls (16 asm dwordx2 sc0) BEFORE phase A so
// the 32 phase-A MFMAs hide the L2 RT; vmcnt(0)+sched_barrier(0) fence (rule
// 18); tag check + swizzle-free LINEAR LDS staging (round-4's XOR swizzle was
// wrong math: it concentrated 16 lanes/bank-window, conflicts 2.1e7->7.1e7;
// for 16-B-aligned ds_read_b128, 8 lanes/window is the geometric floor).
__global__ __launch_bounds__(256, 1) void lstm_main(
    const unsigned short* __restrict__ xb,   // [B][T][I] bf16
    const float* __restrict__ c0,
    const float* __restrict__ b_ih, const float* __restrict__ b_hh,
    const unsigned short* __restrict__ wihp, const unsigned short* __restrict__ whhp,
    unsigned long long* __restrict__ hw64,   // 2 x [16 bg][16 b][256 w] tagged words
    unsigned long long* __restrict__ cnt64,  // [0]: per-XCD byte counters, [1]: total
    float* __restrict__ out)
{
  const int tid  = threadIdx.x;
  const int lane = tid & 63;
  const int w    = tid >> 6;           // wave id == gate type (i,f,g,o)
  const int q    = lane >> 4;
  const int c16  = lane & 15;

  __shared__ float glds[4 * 528];                       // gates [gate][b*33 + jj]
  __shared__ __align__(16) unsigned int hpad[16 * 260]; // h_{t-1} [b][260 w] linear
  __shared__ int s_bg, s_hg, s_agent;

  // ---- XCD-aware role assignment (one-time) ----
  int xcd;
  asm volatile("s_getreg_b32 %0, hwreg(20, 0, 32)" : "=s"(xcd));
  xcd &= 7;
  if (tid == 0) {
    unsigned long long old = __hip_atomic_fetch_add(
        &cnt64[0], 1ull << (8 * xcd), __ATOMIC_RELAXED, __HIP_MEMORY_SCOPE_SYSTEM);
    int r = (int)((old >> (8 * xcd)) & 0xFF);          // local rank on this XCD
    __hip_atomic_fetch_add(&cnt64[1], 1ull, __ATOMIC_RELEASE, __HIP_MEMORY_SCOPE_SYSTEM);
    unsigned long long tot;
    do {
      __builtin_amdgcn_s_sleep(2);
      tot = __hip_atomic_load(&cnt64[1], __ATOMIC_ACQUIRE, __HIP_MEMORY_SCOPE_SYSTEM);
    } while (tot < 256);
    unsigned long long cnts =
        __hip_atomic_load(&cnt64[0], __ATOMIC_RELAXED, __HIP_MEMORY_SCOPE_SYSTEM);
    int base = 0;
#pragma unroll
    for (int x2 = 0; x2 < 8; ++x2) {
      int c = (int)((cnts >> (8 * x2)) & 0xFF);
      if (x2 < xcd) base += c;
    }
    int slot = base + r;
    s_bg = slot >> 4;
    s_hg = slot & 15;
    // agent scope iff this block's whole group fits in one XCD's slot run
    int g0 = slot & ~15;
    int acc = 0, ag = 0;
#pragma unroll
    for (int x2 = 0; x2 < 8; ++x2) {
      int c = (int)((cnts >> (8 * x2)) & 0xFF);
      if (g0 >= acc && g0 + 16 <= acc + c) ag = 1;
      acc += c;
    }
    s_agent = ag;
  }
  __syncthreads();
  const int bg = s_bg;
  const int hg = s_hg;
  const bool agent_path = (s_agent != 0);
  const int s0 = hg * 32;

  // ---- resident weight fragments
  bf16x8 wih[2][16], whh[2][16];
#pragma unroll
  for (int nt = 0; nt < 2; ++nt) {
#pragma unroll
    for (int ks = 0; ks < 16; ++ks) {
      int idc = ((hg * 4 + w) * 2 + nt) * 16 + ks;
      long off = ((long)(idc * 64 + lane)) * 8;
      wih[nt][ks] = __builtin_bit_cast(bf16x8, *(const short8*)(wihp + off));
      whh[nt][ks] = __builtin_bit_cast(bf16x8, *(const short8*)(whhp + off));
    }
  }

  // ---- per-thread recurrent state: 2 items (b = tid>>5 and +8, jj = tid&31)
  const int jj  = tid & 31;
  const int bl0 = tid >> 5;            // 0..7
  const int bglob0 = bg * 16 + bl0;
  const int bglob1 = bglob0 + 8;
  float bias_v[4];
#pragma unroll
  for (int g = 0; g < 4; ++g)
    bias_v[g] = b_ih[g * 512 + s0 + jj] + b_hh[g * 512 + s0 + jj];
  float cst0 = c0[(long)bglob0 * H_SZ + s0 + jj];
  float cst1 = c0[(long)bglob1 * H_SZ + s0 + jj];
  float m0 = -INFINITY, m1 = -INFINITY;

  const unsigned short* xbase = xb + (long)(bg * 16 + c16) * T_SZ * I_SZ + q * 8;

  // consumer-side exchange geometry: thread <-> one producer WAVE
  const int p   = tid >> 4;            // producer block (hg')
  const int wv  = (tid >> 2) & 3;      // producer wave within that block
  const int cq  = tid & 3;             // 16-B quad within the 16-word slice
  const int colbase = p * 16 + cq * 4; // hpad col base (linear)

  // ---- x prefetch for t = 0 (asm, invisible; drained by first loop-top wait)
  bf16x8 xr[16];
  {
    const unsigned short* xn = xbase;
    LDX16(xr[0],  xn, "0");   LDX16(xr[1],  xn, "64");
    LDX16(xr[2],  xn, "128"); LDX16(xr[3],  xn, "192");
    LDX16(xr[4],  xn, "256"); LDX16(xr[5],  xn, "320");
    LDX16(xr[6],  xn, "384"); LDX16(xr[7],  xn, "448");
    LDX16(xr[8],  xn, "512"); LDX16(xr[9],  xn, "576");
    LDX16(xr[10], xn, "640"); LDX16(xr[11], xn, "704");
    LDX16(xr[12], xn, "768"); LDX16(xr[13], xn, "832");
    LDX16(xr[14], xn, "896"); LDX16(xr[15], xn, "960");
  }

#pragma unroll 1
  for (int t = 0; t < T_SZ; ++t) {
    // ---- loop top: xr ready (issued ~1300cy ago); residual store-acks drain
    asm volatile("s_waitcnt vmcnt(0)" ::: "memory");
    __builtin_amdgcn_sched_barrier(0);

    // ---- issue early polls for h_{t-1} (tag t, buffer (t+1)&1)
    const unsigned long long* srcb = hw64 + ((t + 1) & 1) * 65536 + bg * 4096 + colbase;
    const unsigned long long* blo = srcb + 2 * wv * 256;   // rows 2wv, 2wv+1
    const unsigned long long* bhi = blo + 8 * 256;         // rows 2wv+8, 2wv+9
    unsigned long long pv[16];
    if (agent_path) {
      LDPA(pv[0],  blo, "0");    LDPA(pv[1],  blo, "8");
      LDPA(pv[2],  blo, "16");   LDPA(pv[3],  blo, "24");
      LDPA(pv[4],  blo, "2048"); LDPA(pv[5],  blo, "2056");
      LDPA(pv[6],  blo, "2064"); LDPA(pv[7],  blo, "2072");
      LDPA(pv[8],  bhi, "0");    LDPA(pv[9],  bhi, "8");
      LDPA(pv[10], bhi, "16");   LDPA(pv[11], bhi, "24");
      LDPA(pv[12], bhi, "2048"); LDPA(pv[13], bhi, "2056");
      LDPA(pv[14], bhi, "2064"); LDPA(pv[15], bhi, "2072");
    } else {
      LDPS(pv[0],  blo, "0");    LDPS(pv[1],  blo, "8");
      LDPS(pv[2],  blo, "16");   LDPS(pv[3],  blo, "24");
      LDPS(pv[4],  blo, "2048"); LDPS(pv[5],  blo, "2056");
      LDPS(pv[6],  blo, "2064"); LDPS(pv[7],  blo, "2072");
      LDPS(pv[8],  bhi, "0");    LDPS(pv[9],  bhi, "8");
      LDPS(pv[10], bhi, "16");   LDPS(pv[11], bhi, "24");
      LDPS(pv[12], bhi, "2048"); LDPS(pv[13], bhi, "2056");
      LDPS(pv[14], bhi, "2064"); LDPS(pv[15], bhi, "2072");
    }

    // ---- phase A: x projection (MFMA-only; hides the poll L2 round trip)
    f32x4 acc0 = {0.f, 0.f, 0.f, 0.f};
    f32x4 acc1 = {0.f, 0.f, 0.f, 0.f};
#pragma unroll
    for (int ks = 0; ks < 16; ++ks) {
      bf16x8 a = xr[ks];
      acc0 = __builtin_amdgcn_mfma_f32_16x16x32_bf16(a, wih[0][ks], acc0, 0, 0, 0);
      acc1 = __builtin_amdgcn_mfma_f32_16x16x32_bf16(a, wih[1][ks], acc1, 0, 0, 0);
    }

    // ---- polls complete; fence against VALU hoisting (rule 18)
    asm volatile("s_waitcnt vmcnt(0)" ::: "memory");
    __builtin_amdgcn_sched_barrier(0);

    // ---- tag check (steady state: zero reloads) + stage to LINEAR LDS
    if (agent_path) poll_check<__HIP_MEMORY_SCOPE_AGENT>(pv, srcb, wv, (unsigned)t);
    else            poll_check<__HIP_MEMORY_SCOPE_SYSTEM>(pv, srcb, wv, (unsigned)t);
#pragma unroll
    for (int g = 0; g < 4; ++g) {
      const int row = 2 * wv + (g & 1) + (g >> 1) * 8;
      uint4v d = {(unsigned int)pv[g * 4 + 0], (unsigned int)pv[g * 4 + 1],
                  (unsigned int)pv[g * 4 + 2], (unsigned int)pv[g * 4 + 3]};
      *(uint4v*)(hpad + row * 260 + colbase) = d;
    }
    __syncthreads();

    // ---- x_{t+1} prefetch (asm, invisible; retired by next loop-top wait)
    {
      const unsigned short* xn = xbase + (long)(t + 1 < T_SZ ? t + 1 : t) * I_SZ;
      LDX16(xr[0],  xn, "0");   LDX16(xr[1],  xn, "64");
      LDX16(xr[2],  xn, "128"); LDX16(xr[3],  xn, "192");
      LDX16(xr[4],  xn, "256"); LDX16(xr[5],  xn, "320");
      LDX16(xr[6],  xn, "384"); LDX16(xr[7],  xn, "448");
      LDX16(xr[8],  xn, "512"); LDX16(xr[9],  xn, "576");
      LDX16(xr[10], xn, "640"); LDX16(xr[11], xn, "704");
      LDX16(xr[12], xn, "768"); LDX16(xr[13], xn, "832");
      LDX16(xr[14], xn, "896"); LDX16(xr[15], xn, "960");
    }

    // ---- phase C: recurrent projection from LDS (linear)
    const unsigned int* hrow = hpad + c16 * 260;
#pragma unroll
    for (int ks = 0; ks < 16; ++ks) {
      bf16x8 a = __builtin_bit_cast(bf16x8, *(const short8*)(hrow + ks * 16 + q * 4));
      acc0 = __builtin_amdgcn_mfma_f32_16x16x32_bf16(a, whh[0][ks], acc0, 0, 0, 0);
      acc1 = __builtin_amdgcn_mfma_f32_16x16x32_bf16(a, whh[1][ks], acc1, 0, 0, 0);
    }

    // ---- phase D: gates -> LDS (D layout: row=q*4+r (batch), col=lane&15)
#pragma unroll
    for (int r = 0; r < 4; ++r) {
      glds[w * 528 + (q * 4 + r) * 33 + c16]      = acc0[r];
      glds[w * 528 + (q * 4 + r) * 33 + 16 + c16] = acc1[r];
    }
    __syncthreads();

    // ---- phase E: cell math, then IMMEDIATELY publish h (fire-and-forget)
    float hv0, hv1;
#pragma unroll
    for (int it = 0; it < 2; ++it) {
      int b = bl0 + it * 8;
      float gi = glds[0 * 528 + b * 33 + jj] + bias_v[0];
      float gf = glds[1 * 528 + b * 33 + jj] + bias_v[1];
      float gg = glds[2 * 528 + b * 33 + jj] + bias_v[2];
      float go = glds[3 * 528 + b * 33 + jj] + bias_v[3];
      float& cs = it ? cst1 : cst0;
      cs = sigm(gf) * cs + sigm(gi) * tanh_(gg);
      float h = sigm(go) * tanh_(cs);
      if (it) hv1 = h; else hv0 = h;
    }
    {
      float po0 = __shfl_xor(hv0, 1);
      float po1 = __shfl_xor(hv1, 1);
      if (!(jj & 1)) {
        unsigned long long tagw = (unsigned long long)(t + 1) << 32;
        unsigned long long w0 = tagw | ((unsigned)f2bf(hv0) | ((unsigned)f2bf(po0) << 16));
        unsigned long long w1 = tagw | ((unsigned)f2bf(hv1) | ((unsigned)f2bf(po1) << 16));
        unsigned long long* d0 = hw64 + (t & 1) * 65536 + bg * 4096
                               + bl0 * 256 + (s0 >> 1) + (jj >> 1);
        if (agent_path) {
          st64<__HIP_MEMORY_SCOPE_AGENT>(d0, w0);
          st64<__HIP_MEMORY_SCOPE_AGENT>(d0 + 8 * 256, w1);
        } else {
          st64<__HIP_MEMORY_SCOPE_SYSTEM>(d0, w0);
          st64<__HIP_MEMORY_SCOPE_SYSTEM>(d0 + 8 * 256, w1);
        }
      }
    }

    // ---- phase F: outputs (off the critical path, after h is in flight)
#pragma unroll
    for (int it = 0; it < 2; ++it) {
      int b   = bl0 + it * 8;
      int bgl = bg * 16 + b;
      float h = it ? hv1 : hv0;
      float& mm = it ? m1 : m0;
      if (hg < 8) {
        mm = fmaxf(mm, h);
        out[(long)bgl * (T_SZ * HALF) + t * HALF + s0 + jj] = mm;
      } else {
        out[(long)(256 + bgl) * (T_SZ * HALF) + t * HALF + (s0 - 256) + jj] = h;
      }
      if (t == T_SZ - 1) {
        float cs = it ? cst1 : cst0;
        out[33554432L + (long)bgl * H_SZ + s0 + jj] = h;
        out[33554432L + 131072L + (long)bgl * H_SZ + s0 + jj] = cs;
      }
    }
  }
}

extern "C" void kernel_launch(void* const* d_in, const int* in_sizes, int n_in,
                              void* d_out, int out_size, void* d_ws, size_t ws_size,
                              hipStream_t stream) {
  const float* x   = (const float*)d_in[0];
  const float* h0  = (const float*)d_in[1];
  const float* c0  = (const float*)d_in[2];
  const float* Wih = (const float*)d_in[3];
  const float* Whh = (const float*)d_in[4];
  const float* bih = (const float*)d_in[5];
  const float* bhh = (const float*)d_in[6];
  float* out = (float*)d_out;

  char* ws = (char*)d_ws;
  unsigned short* xb     = (unsigned short*)(ws);              // 67,108,864 B
  unsigned short* wihp   = (unsigned short*)(ws + 67108864);   //  2,097,152 B
  unsigned short* whhp   = (unsigned short*)(ws + 69206016);   //  2,097,152 B
  unsigned long long* hw = (unsigned long long*)(ws + 71303168); // 1,048,576 B
  unsigned long long* cn = (unsigned long long*)(ws + 72351744); //     4,096 B

  hipMemsetAsync(cn, 0, 4096, stream);
  cvt_f32_bf16<<<16384, 256, 0, stream>>>(x, xb);              // x -> bf16
  init_hw<<<256, 256, 0, stream>>>(h0, hw);                    // buf1 tag0 + buf0 poison
  pack_w<<<1024, 256, 0, stream>>>(Wih, Whh, wihp, whhp);
  lstm_main<<<256, 256, 0, stream>>>(xb, c0, bih, bhh, wihp, whhp, hw, cn, out);
}